// Round 1
// 2051.479 us; speedup vs baseline: 3.9639x; 3.9639x over previous
//
#include <hip/hip_runtime.h>
#include <stdint.h>

#define B_ 16384
#define S_ 336
#define T_ 48
#define IN_ 5
#define H_ 64

typedef _Float16 f16;
typedef _Float16 f16x8 __attribute__((ext_vector_type(8)));
typedef float f32x4 __attribute__((ext_vector_type(4)));

// ---- ws layout (float words) ----
// A-fragment packed weights: [mt16][kt][lane64][pl2][reg4] u32 words
#define OFF_E0 0            // enc L0: K=96 (x:5 pad->32, h0:64), 16*3*512 = 24576
#define OFF_E1 24576        // enc L1: K=128 (h0new, h1prev),    16*4*512 = 32768
#define OFF_D0 57344        // dec L0: K=96 (x:1 pad->32, h0:64)
#define OFF_D1 81920        // dec L1: K=128
#define OFF_BE0 114688      // biases, gp-order (gp = 4u+type), 256 each
#define OFF_BE1 114944
#define OFF_BD0 115200
#define OFF_BD1 115456
#define OFF_FCW 115712
#define OFF_FCB 115776
#define WS_TOT  115777

__device__ __forceinline__ float fsig(float x) {
    return __builtin_amdgcn_rcpf(1.0f + __expf(-x));
}
__device__ __forceinline__ float ftanh(float x) {
    return 1.0f - 2.0f * __builtin_amdgcn_rcpf(1.0f + __expf(2.0f * x));
}

// ---------------- prep: pack weights into MFMA A-fragment layout, f16 hi/lo ----
// frag word idx decode: reg = i&3, pl = (i>>2)&1, lane = (i>>3)&63, rest = i>>9,
// kt = rest%nkt, mt = rest/nkt.
// element: gp = mt*16 + (lane&15); u = gp>>2; type = gp&3; orig row j = type*64+u;
// k = kt*32 + (lane>>4)*8 + reg*2 + half   (same (group,elem)->k map used for B side)
__global__ void prep_kernel(
    const float* __restrict__ eWih0, const float* __restrict__ eWhh0,
    const float* __restrict__ ebih0, const float* __restrict__ ebhh0,
    const float* __restrict__ eWih1, const float* __restrict__ eWhh1,
    const float* __restrict__ ebih1, const float* __restrict__ ebhh1,
    const float* __restrict__ dWih0, const float* __restrict__ dWhh0,
    const float* __restrict__ dbih0, const float* __restrict__ dbhh0,
    const float* __restrict__ dWih1, const float* __restrict__ dWhh1,
    const float* __restrict__ dbih1, const float* __restrict__ dbhh1,
    const float* __restrict__ fcW,  const float* __restrict__ fcb,
    float* __restrict__ ws)
{
    int idx = blockIdx.x * blockDim.x + threadIdx.x;
    if (idx >= WS_TOT) return;
    float outv;
    if (idx < OFF_BE0) {
        int rel, nkt, xdim;
        const float *Wi, *Wh;
        if (idx < OFF_E1)      { rel = idx - OFF_E0; nkt = 3; xdim = IN_; Wi = eWih0; Wh = eWhh0; }
        else if (idx < OFF_D0) { rel = idx - OFF_E1; nkt = 4; xdim = 64;  Wi = eWih1; Wh = eWhh1; }
        else if (idx < OFF_D1) { rel = idx - OFF_D0; nkt = 3; xdim = 1;   Wi = dWih0; Wh = dWhh0; }
        else                   { rel = idx - OFF_D1; nkt = 4; xdim = 64;  Wi = dWih1; Wh = dWhh1; }
        int reg = rel & 3, pl = (rel >> 2) & 1, lane = (rel >> 3) & 63;
        int rest = rel >> 9;
        int kt = rest % nkt, mt = rest / nkt;
        int gp = mt * 16 + (lane & 15);
        int j  = (gp & 3) * 64 + (gp >> 2);
        union { f16 h2[2]; float f; } u_;
        #pragma unroll
        for (int h = 0; h < 2; ++h) {
            int k = kt * 32 + (lane >> 4) * 8 + reg * 2 + h;
            float v;
            if (nkt == 4) v = (k < 64) ? Wi[j * 64 + k] : Wh[j * 64 + (k - 64)];
            else          v = (k < xdim) ? Wi[j * xdim + k]
                              : ((k < 32) ? 0.0f : Wh[j * 64 + (k - 32)]);
            f16 hi = (f16)v;
            u_.h2[h] = (pl == 0) ? hi : (f16)(v - (float)hi);
        }
        outv = u_.f;
    } else if (idx < OFF_FCW) {
        int rel = idx - OFF_BE0;
        int which = rel >> 8, gp = rel & 255;
        int j = (gp & 3) * 64 + (gp >> 2);
        const float *bi, *bh;
        if (which == 0)      { bi = ebih0; bh = ebhh0; }
        else if (which == 1) { bi = ebih1; bh = ebhh1; }
        else if (which == 2) { bi = dbih0; bh = dbhh0; }
        else                 { bi = dbih1; bh = dbhh1; }
        outv = bi[j] + bh[j];
    } else if (idx < OFF_FCB) {
        outv = fcW[idx - OFF_FCW];
    } else {
        outv = fcb[0];
    }
    ws[idx] = outv;
}

// LDS index helpers (f16 element index)
// XB : [buf2][pl2][g4 4][row64][i8]      x staging, kt0 of L0 operand
// HB : [buf2][pl2][kt2][g4 4][row64][i8] h0/h1 in B-frag layout, k = kt*32+g4*8+i = u
#define XBI(b,p,g,r)   ((((((b)*2)+(p))*4+(g))*64+(r))*8)
#define HBI(b,p,k,g,r) (((((((b)*2)+(p))*2+(k))*4+(g))*64+(r))*8)

#define MFMA(a,b,c) __builtin_amdgcn_mfma_f32_16x16x32_f16(a, b, c, 0, 0, 0)

// One LSTM timestep (both layers). Caller issues the final barrier.
template<bool DEC>
__device__ __forceinline__ void lstm_step(
    int cur, int m0, int lane,
    const f16x8 (&wa)[7][2][2],
    const f32x4 (&bias0)[2], const f32x4 (&bias1)[2],
    float (&c0)[2][4], float (&c1)[2][4],
    f16* __restrict__ XB, f16* __restrict__ H0B, f16* __restrict__ H1B,
    float* __restrict__ H1F)
{
    const int nxt = cur ^ 1;
    const int g4 = lane >> 4, l15 = lane & 15;
    f32x4 acc[2][4];

    // ---- layer 0: gates = W0 @ [x | pad | h0_prev] + b0
    #pragma unroll
    for (int mt = 0; mt < 2; ++mt)
        #pragma unroll
        for (int nt = 0; nt < 4; ++nt) acc[mt][nt] = bias0[mt];
    #pragma unroll
    for (int nt = 0; nt < 4; ++nt) {
        const int r = nt * 16 + l15;
        f16x8 b0h = *(const f16x8*)&XB [XBI(cur,0,g4,r)];
        f16x8 b0l = *(const f16x8*)&XB [XBI(cur,1,g4,r)];
        f16x8 b1h = *(const f16x8*)&H0B[HBI(cur,0,0,g4,r)];
        f16x8 b1l = *(const f16x8*)&H0B[HBI(cur,1,0,g4,r)];
        f16x8 b2h = *(const f16x8*)&H0B[HBI(cur,0,1,g4,r)];
        f16x8 b2l = *(const f16x8*)&H0B[HBI(cur,1,1,g4,r)];
        #pragma unroll
        for (int mt = 0; mt < 2; ++mt) {
            f32x4 a = acc[mt][nt];
            a = MFMA(wa[0][mt][0], b0h, a);
            a = MFMA(wa[0][mt][1], b0h, a);
            a = MFMA(wa[0][mt][0], b0l, a);
            a = MFMA(wa[1][mt][0], b1h, a);
            a = MFMA(wa[1][mt][1], b1h, a);
            a = MFMA(wa[1][mt][0], b1l, a);
            a = MFMA(wa[2][mt][0], b2h, a);
            a = MFMA(wa[2][mt][1], b2h, a);
            a = MFMA(wa[2][mt][0], b2l, a);
            acc[mt][nt] = a;
        }
    }
    // activation L0 -> h0_new into H0B[nxt]  (lane-local: regs 0..3 = i,f,g,o of unit u)
    #pragma unroll
    for (int mt = 0; mt < 2; ++mt) {
        const int u = (m0 + mt) * 4 + g4;
        const int bh_ = HBI(nxt,0,(u>>5),(u>>3)&3,0) + (u & 7);
        const int bl_ = HBI(nxt,1,(u>>5),(u>>3)&3,0) + (u & 7);
        #pragma unroll
        for (int nt = 0; nt < 4; ++nt) {
            f32x4 g = acc[mt][nt];
            float ig = fsig(g[0]), fg = fsig(g[1]);
            float gg = ftanh(g[2]), og = fsig(g[3]);
            float c = fmaf(fg, c0[mt][nt], ig * gg);
            c0[mt][nt] = c;
            float h = og * ftanh(c);
            f16 hh = (f16)h;
            f16 hl = (f16)(h - (float)hh);
            const int r = nt * 16 + l15;
            H0B[bh_ + r * 8] = hh;
            H0B[bl_ + r * 8] = hl;
        }
    }
    __syncthreads();

    // ---- layer 1: gates = W1 @ [h0_new | h1_prev] + b1
    #pragma unroll
    for (int mt = 0; mt < 2; ++mt)
        #pragma unroll
        for (int nt = 0; nt < 4; ++nt) acc[mt][nt] = bias1[mt];
    #pragma unroll
    for (int nt = 0; nt < 4; ++nt) {
        const int r = nt * 16 + l15;
        f16x8 b0h = *(const f16x8*)&H0B[HBI(nxt,0,0,g4,r)];
        f16x8 b0l = *(const f16x8*)&H0B[HBI(nxt,1,0,g4,r)];
        f16x8 b1h = *(const f16x8*)&H0B[HBI(nxt,0,1,g4,r)];
        f16x8 b1l = *(const f16x8*)&H0B[HBI(nxt,1,1,g4,r)];
        f16x8 b2h = *(const f16x8*)&H1B[HBI(cur,0,0,g4,r)];
        f16x8 b2l = *(const f16x8*)&H1B[HBI(cur,1,0,g4,r)];
        f16x8 b3h = *(const f16x8*)&H1B[HBI(cur,0,1,g4,r)];
        f16x8 b3l = *(const f16x8*)&H1B[HBI(cur,1,1,g4,r)];
        #pragma unroll
        for (int mt = 0; mt < 2; ++mt) {
            f32x4 a = acc[mt][nt];
            a = MFMA(wa[3][mt][0], b0h, a);
            a = MFMA(wa[3][mt][1], b0h, a);
            a = MFMA(wa[3][mt][0], b0l, a);
            a = MFMA(wa[4][mt][0], b1h, a);
            a = MFMA(wa[4][mt][1], b1h, a);
            a = MFMA(wa[4][mt][0], b1l, a);
            a = MFMA(wa[5][mt][0], b2h, a);
            a = MFMA(wa[5][mt][1], b2h, a);
            a = MFMA(wa[5][mt][0], b2l, a);
            a = MFMA(wa[6][mt][0], b3h, a);
            a = MFMA(wa[6][mt][1], b3h, a);
            a = MFMA(wa[6][mt][0], b3l, a);
            acc[mt][nt] = a;
        }
    }
    // activation L1 -> h1_new into H1B[nxt] (+ fp32 copy for fc head in decoder)
    #pragma unroll
    for (int mt = 0; mt < 2; ++mt) {
        const int u = (m0 + mt) * 4 + g4;
        const int bh_ = HBI(nxt,0,(u>>5),(u>>3)&3,0) + (u & 7);
        const int bl_ = HBI(nxt,1,(u>>5),(u>>3)&3,0) + (u & 7);
        #pragma unroll
        for (int nt = 0; nt < 4; ++nt) {
            f32x4 g = acc[mt][nt];
            float ig = fsig(g[0]), fg = fsig(g[1]);
            float gg = ftanh(g[2]), og = fsig(g[3]);
            float c = fmaf(fg, c1[mt][nt], ig * gg);
            c1[mt][nt] = c;
            float h = og * ftanh(c);
            f16 hh = (f16)h;
            f16 hl = (f16)(h - (float)hh);
            const int r = nt * 16 + l15;
            H1B[bh_ + r * 8] = hh;
            H1B[bl_ + r * 8] = hl;
            if (DEC) H1F[u * 64 + r] = h;
        }
    }
}

// 512 threads = 8 waves; wave w owns packed-gate M-tiles {2w,2w+1} (units 8w..8w+7);
// 64 batch rows per block; grid = 256. Weights persist in VGPRs (A-frags).
__global__ __launch_bounds__(512, 2) void lstm_kernel(
    const float* __restrict__ src, const float* __restrict__ ws,
    float* __restrict__ out)
{
    __shared__ __align__(16) f16 XB [2*2*4*64*8];     // 16 KB
    __shared__ __align__(16) f16 H0B[2*2*2*4*64*8];   // 32 KB
    __shared__ __align__(16) f16 H1B[2*2*2*4*64*8];   // 32 KB
    __shared__ float H1F[64*64];                      // 16 KB (decoder fc)
    __shared__ float FCW[64];

    const int tid  = threadIdx.x;
    const int lane = tid & 63;
    const int wave = __builtin_amdgcn_readfirstlane(tid >> 6);
    const int m0   = wave * 2;
    const int g4   = lane >> 4;
    const int rowBase = blockIdx.x * 64;

    float c0[2][4], c1[2][4];
    #pragma unroll
    for (int mt = 0; mt < 2; ++mt)
        #pragma unroll
        for (int nt = 0; nt < 4; ++nt) { c0[mt][nt] = 0.0f; c1[mt][nt] = 0.0f; }

    f16x8 wa[7][2][2];          // [kt: 0-2 L0, 3-6 L1][mt][hi/lo]
    f32x4 bias0[2], bias1[2];

    auto ldw = [&](int off0, int off1, int ob0, int ob1) {
        #pragma unroll
        for (int kt = 0; kt < 3; ++kt)
            #pragma unroll
            for (int mt = 0; mt < 2; ++mt)
                #pragma unroll
                for (int pl = 0; pl < 2; ++pl)
                    wa[kt][mt][pl] = *(const f16x8*)(ws + off0 +
                        ((((m0 + mt) * 3 + kt) * 64 + lane) * 2 + pl) * 4);
        #pragma unroll
        for (int kt = 0; kt < 4; ++kt)
            #pragma unroll
            for (int mt = 0; mt < 2; ++mt)
                #pragma unroll
                for (int pl = 0; pl < 2; ++pl)
                    wa[3 + kt][mt][pl] = *(const f16x8*)(ws + off1 +
                        ((((m0 + mt) * 4 + kt) * 64 + lane) * 2 + pl) * 4);
        #pragma unroll
        for (int mt = 0; mt < 2; ++mt) {
            bias0[mt] = *(const f32x4*)(ws + ob0 + (m0 + mt) * 16 + g4 * 4);
            bias1[mt] = *(const f32x4*)(ws + ob1 + (m0 + mt) * 16 + g4 * 4);
        }
    };
    ldw(OFF_E0, OFF_E1, OFF_BE0, OFF_BE1);

    // zero buf 0 of h states (buf0 = first 8192 f16 of each array)
    for (int i = tid; i < 8192; i += 512) { H0B[i] = (f16)0; H1B[i] = (f16)0; }
    if (tid < 64) FCW[tid] = ws[OFF_FCW + tid];
    const float fcbv = ws[OFF_FCB];

    const float* sp = src + (size_t)(rowBase + lane) * (S_ * IN_);

    // stage x[0] (wave 7: lane = row)
    if (wave == 7) {
        f16x8 ph, pl_;
        #pragma unroll
        for (int i = 0; i < 8; ++i) { ph[i] = (f16)0; pl_[i] = (f16)0; }
        #pragma unroll
        for (int i = 0; i < 5; ++i) {
            float v = sp[i];
            f16 hh = (f16)v; ph[i] = hh; pl_[i] = (f16)(v - (float)hh);
        }
        *(f16x8*)&XB[XBI(0,0,0,lane)] = ph;
        *(f16x8*)&XB[XBI(0,1,0,lane)] = pl_;
    }
    __syncthreads();

    int cur = 0;
    // ---------------- encoder ----------------
    #pragma unroll 1
    for (int t = 0; t < S_; ++t) {
        float xv[5];
        const bool pf = (wave == 7) && (t + 1 < S_);
        if (pf) {
            #pragma unroll
            for (int i = 0; i < 5; ++i) xv[i] = sp[(t + 1) * 5 + i];
        }
        lstm_step<false>(cur, m0, lane, wa, bias0, bias1, c0, c1, XB, H0B, H1B, H1F);
        if (pf) {
            const int nxt = cur ^ 1;
            f16x8 ph, pl_;
            #pragma unroll
            for (int i = 0; i < 8; ++i) { ph[i] = (f16)0; pl_[i] = (f16)0; }
            #pragma unroll
            for (int i = 0; i < 5; ++i) {
                f16 hh = (f16)xv[i]; ph[i] = hh; pl_[i] = (f16)(xv[i] - (float)hh);
            }
            *(f16x8*)&XB[XBI(nxt,0,0,lane)] = ph;
            *(f16x8*)&XB[XBI(nxt,1,0,lane)] = pl_;
        }
        __syncthreads();
        cur ^= 1;
    }

    // ---------------- decoder ----------------
    ldw(OFF_D0, OFF_D1, OFF_BD0, OFF_BD1);
    if (wave == 7) {
        float v = sp[(S_ - 1) * IN_ + 3];   // dec_in0 = src[:, -1, 3]
        f16x8 ph, pl_;
        #pragma unroll
        for (int i = 0; i < 8; ++i) { ph[i] = (f16)0; pl_[i] = (f16)0; }
        f16 hh = (f16)v; ph[0] = hh; pl_[0] = (f16)(v - (float)hh);
        *(f16x8*)&XB[XBI(cur,0,0,lane)] = ph;
        *(f16x8*)&XB[XBI(cur,1,0,lane)] = pl_;
    }
    __syncthreads();

    #pragma unroll 1
    for (int t = 0; t < T_; ++t) {
        lstm_step<true>(cur, m0, lane, wa, bias0, bias1, c0, c1, XB, H0B, H1B, H1F);
        __syncthreads();
        const int nxt = cur ^ 1;
        if (wave == 0) {   // fc head: pred = fcW . h1_new + fcb  (lane = row)
            float p = fcbv;
            #pragma unroll
            for (int k = 0; k < 64; ++k) p = fmaf(FCW[k], H1F[k * 64 + lane], p);
            out[(size_t)(rowBase + lane) * T_ + t] = p;
            f16x8 ph, pl_;
            #pragma unroll
            for (int i = 0; i < 8; ++i) { ph[i] = (f16)0; pl_[i] = (f16)0; }
            f16 hh = (f16)p; ph[0] = hh; pl_[0] = (f16)(p - (float)hh);
            *(f16x8*)&XB[XBI(nxt,0,0,lane)] = ph;
            *(f16x8*)&XB[XBI(nxt,1,0,lane)] = pl_;
        }
        __syncthreads();
        cur ^= 1;
    }
}

extern "C" void kernel_launch(void* const* d_in, const int* in_sizes, int n_in,
                              void* d_out, int out_size, void* d_ws, size_t ws_size,
                              hipStream_t stream)
{
    const float* src = (const float*)d_in[0];
    float* ws  = (float*)d_ws;
    float* out = (float*)d_out;

    prep_kernel<<<(WS_TOT + 255) / 256, 256, 0, stream>>>(
        (const float*)d_in[1],  (const float*)d_in[2],
        (const float*)d_in[3],  (const float*)d_in[4],
        (const float*)d_in[5],  (const float*)d_in[6],
        (const float*)d_in[7],  (const float*)d_in[8],
        (const float*)d_in[9],  (const float*)d_in[10],
        (const float*)d_in[11], (const float*)d_in[12],
        (const float*)d_in[13], (const float*)d_in[14],
        (const float*)d_in[15], (const float*)d_in[16],
        (const float*)d_in[17], (const float*)d_in[18],
        ws);

    lstm_kernel<<<B_ / 64, 512, 0, stream>>>(src, ws, out);
}

// Round 2
// 1931.794 us; speedup vs baseline: 4.2094x; 1.0620x over previous
//
#include <hip/hip_runtime.h>
#include <stdint.h>

#define B_ 16384
#define S_ 336
#define T_ 48
#define IN_ 5
#define H_ 64

typedef _Float16 f16;
typedef _Float16 f16x8 __attribute__((ext_vector_type(8)));
typedef float f32x4 __attribute__((ext_vector_type(4)));

#define LOG2E 1.44269504088896340736f

// ---- ws layout (float words) ---- (identical geometry to previous round)
// A-fragment packed weights: [mt16][kt][lane64][pl2][reg4] u32 words
// NOTE: weights & biases are PRE-SCALED: rows of gates i,f,o by -log2e,
// rows of gate g by +2*log2e, so activations use raw v_exp_f32 (exp2).
#define OFF_E0 0
#define OFF_E1 24576
#define OFF_D0 57344
#define OFF_D1 81920
#define OFF_BE0 114688
#define OFF_BE1 114944
#define OFF_BD0 115200
#define OFF_BD1 115456
#define OFF_FCW 115712
#define OFF_FCB 115776
#define WS_TOT  115777

__device__ __forceinline__ float sig2(float g) {     // sigmoid(z), g = -log2e*z
    return __builtin_amdgcn_rcpf(1.0f + __builtin_amdgcn_exp2f(g));
}
__device__ __forceinline__ float tanh2(float g) {    // tanh(z), g = 2*log2e*z
    return 1.0f - 2.0f * __builtin_amdgcn_rcpf(1.0f + __builtin_amdgcn_exp2f(g));
}
__device__ __forceinline__ float tanhc(float c) {    // tanh(c), raw c
    return 1.0f - 2.0f * __builtin_amdgcn_rcpf(1.0f + __builtin_amdgcn_exp2f(c * (2.0f * LOG2E)));
}

// ---------------- prep: pack weights into MFMA A-fragment layout, f16 hi/lo ----
__global__ void prep_kernel(
    const float* __restrict__ eWih0, const float* __restrict__ eWhh0,
    const float* __restrict__ ebih0, const float* __restrict__ ebhh0,
    const float* __restrict__ eWih1, const float* __restrict__ eWhh1,
    const float* __restrict__ ebih1, const float* __restrict__ ebhh1,
    const float* __restrict__ dWih0, const float* __restrict__ dWhh0,
    const float* __restrict__ dbih0, const float* __restrict__ dbhh0,
    const float* __restrict__ dWih1, const float* __restrict__ dWhh1,
    const float* __restrict__ dbih1, const float* __restrict__ dbhh1,
    const float* __restrict__ fcW,  const float* __restrict__ fcb,
    float* __restrict__ ws)
{
    int idx = blockIdx.x * blockDim.x + threadIdx.x;
    if (idx >= WS_TOT) return;
    float outv;
    if (idx < OFF_BE0) {
        int rel, nkt, xdim;
        const float *Wi, *Wh;
        if (idx < OFF_E1)      { rel = idx - OFF_E0; nkt = 3; xdim = IN_; Wi = eWih0; Wh = eWhh0; }
        else if (idx < OFF_D0) { rel = idx - OFF_E1; nkt = 4; xdim = 64;  Wi = eWih1; Wh = eWhh1; }
        else if (idx < OFF_D1) { rel = idx - OFF_D0; nkt = 3; xdim = 1;   Wi = dWih0; Wh = dWhh0; }
        else                   { rel = idx - OFF_D1; nkt = 4; xdim = 64;  Wi = dWih1; Wh = dWhh1; }
        int reg = rel & 3, pl = (rel >> 2) & 1, lane = (rel >> 3) & 63;
        int rest = rel >> 9;
        int kt = rest % nkt, mt = rest / nkt;
        int gp = mt * 16 + (lane & 15);
        int type = gp & 3;
        int j  = type * 64 + (gp >> 2);
        float sc = (type == 2) ? (2.0f * LOG2E) : (-LOG2E);
        union { f16 h2[2]; float f; } u_;
        #pragma unroll
        for (int h = 0; h < 2; ++h) {
            int k = kt * 32 + (lane >> 4) * 8 + reg * 2 + h;
            float v;
            if (nkt == 4) v = (k < 64) ? Wi[j * 64 + k] : Wh[j * 64 + (k - 64)];
            else          v = (k < xdim) ? Wi[j * xdim + k]
                              : ((k < 32) ? 0.0f : Wh[j * 64 + (k - 32)]);
            v *= sc;
            f16 hi = (f16)v;
            u_.h2[h] = (pl == 0) ? hi : (f16)(v - (float)hi);
        }
        outv = u_.f;
    } else if (idx < OFF_FCW) {
        int rel = idx - OFF_BE0;
        int which = rel >> 8, gp = rel & 255;
        int type = gp & 3;
        int j = type * 64 + (gp >> 2);
        float sc = (type == 2) ? (2.0f * LOG2E) : (-LOG2E);
        const float *bi, *bh;
        if (which == 0)      { bi = ebih0; bh = ebhh0; }
        else if (which == 1) { bi = ebih1; bh = ebhh1; }
        else if (which == 2) { bi = dbih0; bh = dbhh0; }
        else                 { bi = dbih1; bh = dbhh1; }
        outv = (bi[j] + bh[j]) * sc;
    } else if (idx < OFF_FCB) {
        outv = fcW[idx - OFF_FCW];
    } else {
        outv = fcb[0];
    }
    ws[idx] = outv;
}

// LDS index helpers (f16 element index)
#define XBI(b,p,g,r)   ((((((b)*2)+(p))*4+(g))*64+(r))*8)
#define HBI(b,p,k,g,r) (((((((b)*2)+(p))*2+(k))*4+(g))*64+(r))*8)

#define MFMA(a,b,c) __builtin_amdgcn_mfma_f32_16x16x32_f16(a, b, c, 0, 0, 0)

__device__ __forceinline__ void stage_x5(f16* __restrict__ XB, int b, int lane, const float* xv) {
    f16x8 ph, pl_;
    #pragma unroll
    for (int i = 0; i < 8; ++i) { ph[i] = (f16)0; pl_[i] = (f16)0; }
    #pragma unroll
    for (int i = 0; i < IN_; ++i) {
        f16 hh = (f16)xv[i]; ph[i] = hh; pl_[i] = (f16)(xv[i] - (float)hh);
    }
    *(f16x8*)&XB[XBI(b,0,0,lane)] = ph;
    *(f16x8*)&XB[XBI(b,1,0,lane)] = pl_;
}
__device__ __forceinline__ void stage_x1(f16* __restrict__ XB, int b, int lane, float v) {
    f16x8 ph, pl_;
    #pragma unroll
    for (int i = 0; i < 8; ++i) { ph[i] = (f16)0; pl_[i] = (f16)0; }
    f16 hh = (f16)v; ph[0] = hh; pl_[0] = (f16)(v - (float)hh);
    *(f16x8*)&XB[XBI(b,0,0,lane)] = ph;
    *(f16x8*)&XB[XBI(b,1,0,lane)] = pl_;
}

// ---- standalone layer 0 (prologue + decoder) ----
__device__ __forceinline__ void layer0_only(
    int pX, int pH0r, int pH0w, int m0, int lane,
    const f16x8 (&wa)[7][2][2], const f32x4 (&b0)[2], float (&c0)[2][4],
    const f16* __restrict__ XB, f16* __restrict__ H0B)
{
    const int g4 = lane >> 4, l15 = lane & 15;
    #pragma unroll
    for (int nt = 0; nt < 4; ++nt) {
        const int r = nt * 16 + l15;
        f16x8 xh  = *(const f16x8*)&XB [XBI(pX,0,g4,r)];
        f16x8 xl  = *(const f16x8*)&XB [XBI(pX,1,g4,r)];
        f16x8 hh0 = *(const f16x8*)&H0B[HBI(pH0r,0,0,g4,r)];
        f16x8 hl0 = *(const f16x8*)&H0B[HBI(pH0r,1,0,g4,r)];
        f16x8 hh1 = *(const f16x8*)&H0B[HBI(pH0r,0,1,g4,r)];
        f16x8 hl1 = *(const f16x8*)&H0B[HBI(pH0r,1,1,g4,r)];
        #pragma unroll
        for (int mt = 0; mt < 2; ++mt) {
            f32x4 a = b0[mt];
            a = MFMA(wa[0][mt][0], xh,  a);
            a = MFMA(wa[0][mt][1], xh,  a);
            a = MFMA(wa[0][mt][0], xl,  a);
            a = MFMA(wa[1][mt][0], hh0, a);
            a = MFMA(wa[1][mt][1], hh0, a);
            a = MFMA(wa[1][mt][0], hl0, a);
            a = MFMA(wa[2][mt][0], hh1, a);
            a = MFMA(wa[2][mt][1], hh1, a);
            a = MFMA(wa[2][mt][0], hl1, a);
            const int u = (m0 + mt) * 4 + g4;
            float ig = sig2(a[0]), fg = sig2(a[1]);
            float gg = tanh2(a[2]), og = sig2(a[3]);
            float c = fmaf(fg, c0[mt][nt], ig * gg);
            c0[mt][nt] = c;
            float h = og * tanhc(c);
            f16 hh = (f16)h, hl = (f16)(h - (float)hh);
            H0B[HBI(pH0w,0,(u>>5),(u>>3)&3,r) + (u&7)] = hh;
            H0B[HBI(pH0w,1,(u>>5),(u>>3)&3,r) + (u&7)] = hl;
        }
    }
}

// ---- standalone layer 1 (epilogue + decoder) ----
template<bool DEC>
__device__ __forceinline__ void layer1_only(
    int pH0, int pH1r, int pH1w, int m0, int lane,
    const f16x8 (&wa)[7][2][2], const f32x4 (&b1)[2], float (&c1)[2][4],
    const f16* __restrict__ H0B, f16* __restrict__ H1B, float* __restrict__ H1F)
{
    const int g4 = lane >> 4, l15 = lane & 15;
    #pragma unroll
    for (int nt = 0; nt < 4; ++nt) {
        const int r = nt * 16 + l15;
        f16x8 hh0 = *(const f16x8*)&H0B[HBI(pH0,0,0,g4,r)];
        f16x8 hl0 = *(const f16x8*)&H0B[HBI(pH0,1,0,g4,r)];
        f16x8 hh1 = *(const f16x8*)&H0B[HBI(pH0,0,1,g4,r)];
        f16x8 hl1 = *(const f16x8*)&H0B[HBI(pH0,1,1,g4,r)];
        f16x8 gh0 = *(const f16x8*)&H1B[HBI(pH1r,0,0,g4,r)];
        f16x8 gl0 = *(const f16x8*)&H1B[HBI(pH1r,1,0,g4,r)];
        f16x8 gh1 = *(const f16x8*)&H1B[HBI(pH1r,0,1,g4,r)];
        f16x8 gl1 = *(const f16x8*)&H1B[HBI(pH1r,1,1,g4,r)];
        #pragma unroll
        for (int mt = 0; mt < 2; ++mt) {
            f32x4 a = b1[mt];
            a = MFMA(wa[3][mt][0], hh0, a);
            a = MFMA(wa[3][mt][1], hh0, a);
            a = MFMA(wa[3][mt][0], hl0, a);
            a = MFMA(wa[4][mt][0], hh1, a);
            a = MFMA(wa[4][mt][1], hh1, a);
            a = MFMA(wa[4][mt][0], hl1, a);
            a = MFMA(wa[5][mt][0], gh0, a);
            a = MFMA(wa[5][mt][1], gh0, a);
            a = MFMA(wa[5][mt][0], gl0, a);
            a = MFMA(wa[6][mt][0], gh1, a);
            a = MFMA(wa[6][mt][1], gh1, a);
            a = MFMA(wa[6][mt][0], gl1, a);
            const int u = (m0 + mt) * 4 + g4;
            float ig = sig2(a[0]), fg = sig2(a[1]);
            float gg = tanh2(a[2]), og = sig2(a[3]);
            float c = fmaf(fg, c1[mt][nt], ig * gg);
            c1[mt][nt] = c;
            float h = og * tanhc(c);
            f16 hh = (f16)h, hl = (f16)(h - (float)hh);
            H1B[HBI(pH1w,0,(u>>5),(u>>3)&3,r) + (u&7)] = hh;
            H1B[HBI(pH1w,1,(u>>5),(u>>3)&3,r) + (u&7)] = hl;
            if (DEC) H1F[u * 64 + r] = h;
        }
    }
}

// ---- fused encoder phase t: {L1_t ; L0_{t+1}} — ONE barrier per timestep.
// p = t&1. h0_t in H0B[p]; h1_{t-1} in H1B[p^1]; x_{t+1} in XB[p^1].
// Writes h1_t -> H1B[p], h0_{t+1} -> H0B[p^1]. L1 and L0 SHARE the h0_t frags.
__device__ __forceinline__ void enc_phase(
    int p, int m0, int lane,
    const f16x8 (&wa)[7][2][2], const f32x4 (&b0)[2], const f32x4 (&b1)[2],
    float (&c0)[2][4], float (&c1)[2][4],
    const f16* __restrict__ XB, f16* __restrict__ H0B, f16* __restrict__ H1B)
{
    const int g4 = lane >> 4, l15 = lane & 15;
    const int q = p ^ 1;
    #pragma unroll
    for (int nt = 0; nt < 4; ++nt) {
        const int r = nt * 16 + l15;
        f16x8 hh0 = *(const f16x8*)&H0B[HBI(p,0,0,g4,r)];   // h0_t (shared L1/L0)
        f16x8 hl0 = *(const f16x8*)&H0B[HBI(p,1,0,g4,r)];
        f16x8 hh1 = *(const f16x8*)&H0B[HBI(p,0,1,g4,r)];
        f16x8 hl1 = *(const f16x8*)&H0B[HBI(p,1,1,g4,r)];
        f16x8 gh0 = *(const f16x8*)&H1B[HBI(q,0,0,g4,r)];   // h1_{t-1}
        f16x8 gl0 = *(const f16x8*)&H1B[HBI(q,1,0,g4,r)];
        f16x8 gh1 = *(const f16x8*)&H1B[HBI(q,0,1,g4,r)];
        f16x8 gl1 = *(const f16x8*)&H1B[HBI(q,1,1,g4,r)];
        f16x8 xh  = *(const f16x8*)&XB [XBI(q,0,g4,r)];     // x_{t+1}
        f16x8 xl  = *(const f16x8*)&XB [XBI(q,1,g4,r)];
        #pragma unroll
        for (int mt = 0; mt < 2; ++mt) {
            const int u = (m0 + mt) * 4 + g4;
            // ---- L1_t ----
            f32x4 a = b1[mt];
            a = MFMA(wa[3][mt][0], hh0, a);
            a = MFMA(wa[3][mt][1], hh0, a);
            a = MFMA(wa[3][mt][0], hl0, a);
            a = MFMA(wa[4][mt][0], hh1, a);
            a = MFMA(wa[4][mt][1], hh1, a);
            a = MFMA(wa[4][mt][0], hl1, a);
            a = MFMA(wa[5][mt][0], gh0, a);
            a = MFMA(wa[5][mt][1], gh0, a);
            a = MFMA(wa[5][mt][0], gl0, a);
            a = MFMA(wa[6][mt][0], gh1, a);
            a = MFMA(wa[6][mt][1], gh1, a);
            a = MFMA(wa[6][mt][0], gl1, a);
            {
                float ig = sig2(a[0]), fg = sig2(a[1]);
                float gg = tanh2(a[2]), og = sig2(a[3]);
                float c = fmaf(fg, c1[mt][nt], ig * gg);
                c1[mt][nt] = c;
                float h = og * tanhc(c);
                f16 hh = (f16)h, hl = (f16)(h - (float)hh);
                H1B[HBI(p,0,(u>>5),(u>>3)&3,r) + (u&7)] = hh;
                H1B[HBI(p,1,(u>>5),(u>>3)&3,r) + (u&7)] = hl;
            }
            // ---- L0_{t+1} ----
            f32x4 z = b0[mt];
            z = MFMA(wa[0][mt][0], xh,  z);
            z = MFMA(wa[0][mt][1], xh,  z);
            z = MFMA(wa[0][mt][0], xl,  z);
            z = MFMA(wa[1][mt][0], hh0, z);
            z = MFMA(wa[1][mt][1], hh0, z);
            z = MFMA(wa[1][mt][0], hl0, z);
            z = MFMA(wa[2][mt][0], hh1, z);
            z = MFMA(wa[2][mt][1], hh1, z);
            z = MFMA(wa[2][mt][0], hl1, z);
            {
                float ig = sig2(z[0]), fg = sig2(z[1]);
                float gg = tanh2(z[2]), og = sig2(z[3]);
                float c = fmaf(fg, c0[mt][nt], ig * gg);
                c0[mt][nt] = c;
                float h = og * tanhc(c);
                f16 hh = (f16)h, hl = (f16)(h - (float)hh);
                H0B[HBI(q,0,(u>>5),(u>>3)&3,r) + (u&7)] = hh;
                H0B[HBI(q,1,(u>>5),(u>>3)&3,r) + (u&7)] = hl;
            }
        }
    }
}

// 512 threads = 8 waves; wave w owns packed-gate M-tiles {2w,2w+1} (units 8w..8w+7);
// 64 batch rows per block; grid = 256 (1 block/CU). Weights persist in VGPRs.
__global__ __launch_bounds__(512, 2) void lstm_kernel(
    const float* __restrict__ src, const float* __restrict__ ws,
    float* __restrict__ out)
{
    __shared__ __align__(16) f16 XB [2*2*4*64*8];     // 16 KB
    __shared__ __align__(16) f16 H0B[2*2*2*4*64*8];   // 32 KB
    __shared__ __align__(16) f16 H1B[2*2*2*4*64*8];   // 32 KB
    __shared__ float H1F[64*64];                      // 16 KB (decoder fc)
    __shared__ float FCW[64];

    const int tid  = threadIdx.x;
    const int lane = tid & 63;
    const int wave = __builtin_amdgcn_readfirstlane(tid >> 6);
    const int m0   = wave * 2;
    const int g4   = lane >> 4;
    const int rowBase = blockIdx.x * 64;

    float c0[2][4], c1[2][4];
    #pragma unroll
    for (int mt = 0; mt < 2; ++mt)
        #pragma unroll
        for (int nt = 0; nt < 4; ++nt) { c0[mt][nt] = 0.0f; c1[mt][nt] = 0.0f; }

    f16x8 wa[7][2][2];          // [kt: 0-2 L0, 3-6 L1][mt][hi/lo]
    f32x4 b0[2], b1[2];

    auto ldw = [&](int off0, int off1, int ob0, int ob1) {
        #pragma unroll
        for (int kt = 0; kt < 3; ++kt)
            #pragma unroll
            for (int mt = 0; mt < 2; ++mt)
                #pragma unroll
                for (int pl = 0; pl < 2; ++pl)
                    wa[kt][mt][pl] = *(const f16x8*)(ws + off0 +
                        ((((m0 + mt) * 3 + kt) * 64 + lane) * 2 + pl) * 4);
        #pragma unroll
        for (int kt = 0; kt < 4; ++kt)
            #pragma unroll
            for (int mt = 0; mt < 2; ++mt)
                #pragma unroll
                for (int pl = 0; pl < 2; ++pl)
                    wa[3 + kt][mt][pl] = *(const f16x8*)(ws + off1 +
                        ((((m0 + mt) * 4 + kt) * 64 + lane) * 2 + pl) * 4);
        #pragma unroll
        for (int mt = 0; mt < 2; ++mt) {
            b0[mt] = *(const f32x4*)(ws + ob0 + (m0 + mt) * 16 + g4 * 4);
            b1[mt] = *(const f32x4*)(ws + ob1 + (m0 + mt) * 16 + g4 * 4);
        }
    };
    ldw(OFF_E0, OFF_E1, OFF_BE0, OFF_BE1);

    // zero XB (fully) and parity-1 halves of H0B/H1B (h0_{-1} = h1_{-1} = 0)
    for (int i = tid; i < 2*2*4*64*8; i += 512) XB[i] = (f16)0;
    for (int i = tid; i < 8192; i += 512) { H0B[8192 + i] = (f16)0; H1B[8192 + i] = (f16)0; }
    if (tid < 64) FCW[tid] = ws[OFF_FCW + tid];
    const float fcbv = ws[OFF_FCB];

    const float* sp = src + (size_t)(rowBase + lane) * (S_ * IN_);
    __syncthreads();

    // stage x0 -> XB[0], x1 -> XB[1]
    if (wave == 7) {
        float xv[IN_];
        #pragma unroll
        for (int i = 0; i < IN_; ++i) xv[i] = sp[i];
        stage_x5(XB, 0, lane, xv);
        #pragma unroll
        for (int i = 0; i < IN_; ++i) xv[i] = sp[IN_ + i];
        stage_x5(XB, 1, lane, xv);
    }
    __syncthreads();

    // prologue: L0_0 (reads XB[0], H0B[1](=0), writes H0B[0])
    layer0_only(0, 1, 0, m0, lane, wa, b0, c0, XB, H0B);
    __syncthreads();

    // ---------------- encoder: fused phases, ONE barrier per timestep ----------
    #pragma unroll 1
    for (int t = 0; t < S_ - 1; ++t) {
        const int p = t & 1;
        float xv[IN_];
        const bool pf = (wave == 7) && (t + 2 < S_);
        if (pf) {
            #pragma unroll
            for (int i = 0; i < IN_; ++i) xv[i] = sp[(t + 2) * IN_ + i];
        }
        enc_phase(p, m0, lane, wa, b0, b1, c0, c1, XB, H0B, H1B);
        if (pf) stage_x5(XB, p, lane, xv);   // x_{t+2} -> XB[(t+2)&1] = XB[p]
        __syncthreads();
    }

    // epilogue: L1_{S-1} (reads H0B[1], H1B[0], writes H1B[1])
    layer1_only<false>(1, 0, 1, m0, lane, wa, b1, c1, H0B, H1B, H1F);
    __syncthreads();

    // ---------------- decoder ----------------
    ldw(OFF_D0, OFF_D1, OFF_BD0, OFF_BD1);
    if (wave == 7) stage_x1(XB, 0, lane, sp[(S_ - 1) * IN_ + 3]);   // dec_in0
    __syncthreads();

    #pragma unroll 1
    for (int t = 0; t < T_; ++t) {
        const int q = t & 1;
        layer0_only(q, q ^ 1, q, m0, lane, wa, b0, c0, XB, H0B);
        __syncthreads();
        layer1_only<true>(q, q ^ 1, q, m0, lane, wa, b1, c1, H0B, H1B, H1F);
        __syncthreads();
        if (wave == 0) {   // fc head: pred = fcW . h1_new + fcb  (lane = row)
            float pv = fcbv;
            #pragma unroll 4
            for (int k = 0; k < 64; ++k) pv = fmaf(FCW[k], H1F[k * 64 + lane], pv);
            out[(size_t)(rowBase + lane) * T_ + t] = pv;
            if (t + 1 < T_) stage_x1(XB, q ^ 1, lane, pv);
        }
        __syncthreads();
    }
}

extern "C" void kernel_launch(void* const* d_in, const int* in_sizes, int n_in,
                              void* d_out, int out_size, void* d_ws, size_t ws_size,
                              hipStream_t stream)
{
    const float* src = (const float*)d_in[0];
    float* ws  = (float*)d_ws;
    float* out = (float*)d_out;

    prep_kernel<<<(WS_TOT + 255) / 256, 256, 0, stream>>>(
        (const float*)d_in[1],  (const float*)d_in[2],
        (const float*)d_in[3],  (const float*)d_in[4],
        (const float*)d_in[5],  (const float*)d_in[6],
        (const float*)d_in[7],  (const float*)d_in[8],
        (const float*)d_in[9],  (const float*)d_in[10],
        (const float*)d_in[11], (const float*)d_in[12],
        (const float*)d_in[13], (const float*)d_in[14],
        (const float*)d_in[15], (const float*)d_in[16],
        (const float*)d_in[17], (const float*)d_in[18],
        ws);

    lstm_kernel<<<B_ / 64, 512, 0, stream>>>(src, ws, out);
}